// Round 14
// baseline (90.572 us; speedup 1.0000x reference)
//
#include <hip/hip_runtime.h>
#include <math.h>

#define NUM_H 256
#define NP    64        // poles per h
#define LL    8192      // sequence length
#define NHALF 4096      // LL/2 (complex FFT size)
#define NTA   256       // threads, Cauchy kernel
#define NTB   1024      // threads, FFT kernel

// v_sin_f32 / v_cos_f32 take input in REVOLUTIONS (D = sin(S0 * 2pi)).

// Strength-reduced per-pole coefficients (all precomputed in the LDS table):
//   g  = y^2 - wi^2,  dd = d1*d2 = g^2 + c2*(y^2 + c4),  ir = 1/dd
//   real contrib (per v-combo) = (P*g + Q)*ir
//   imag contrib (per v-combo) = (C*g + D)*y*ir
// with c2 = 2wz, c4 = wz/2 + wi^2, wz = wr^2, wx = -wr, c6 = 4wi^2+2wz,
//   P = 2(wx*vr + wi*vi);  Q = wx*c6*vr - 2wi*wz*vi
//   C = -2vr;              D = -2wz*vr + 4wx*wi*vi
// Verified against the direct i1/i2 form symbolically and at y=0, wz=0.
// Table: s_t[n] = { {nwisq, c4, c2, P0}, {Q0, C0, D0, P1}, {Q1, C1, D1, P2},
//                   {Q2, C2, D2, P3}, {Q3, C3, D3, wi} }   (5 float4 / pole)

// ---------------- Kernel A: Cauchy sum + Woodbury -> spectrum ----------------
__global__ __launch_bounds__(NTA)
void cauchy_phase(const float* __restrict__ w_ri,
                  const float* __restrict__ p_ri,
                  const float* __restrict__ q_ri,
                  const float* __restrict__ B_ri,
                  const float* __restrict__ C_ri,
                  const float* __restrict__ log_dt,
                  float*       __restrict__ spec,   // (H, 4096) float2 rows (= d_out)
                  float2*      __restrict__ nyq)    // (H,) Nyquist bins (= d_ws)
{
    __shared__ float4 s_t[NP][5];

    const int h     = blockIdx.y;
    const int chunk = blockIdx.x;      // 16 chunks of 256 bins
    const int tid   = threadIdx.x;
    const float dt  = expf(log_dt[h]);

    if (tid < NP) {
        const int n = tid;
        const float2 w = ((const float2*)w_ri)[h * NP + n];
        const float2 p = ((const float2*)p_ri)[h * NP + n];
        const float2 q = ((const float2*)q_ri)[h * NP + n];
        const float2 B = ((const float2*)B_ri)[h * NP + n];
        const float2 C = ((const float2*)C_ri)[h * NP + n];
        const float wr = w.x * dt, wi = w.y * dt;
        const float wz = wr * wr, wisq = wi * wi, wx = -wr;
        const float c6 = 4.f * wisq + 2.f * wz;
        const float vr0 = B.x * C.x + B.y * C.y, vi0 = B.y * C.x - B.x * C.y;
        const float vr1 = p.x * C.x + p.y * C.y, vi1 = p.y * C.x - p.x * C.y;
        const float vr2 = B.x * q.x + B.y * q.y, vi2 = B.y * q.x - B.x * q.y;
        const float vr3 = p.x * q.x + p.y * q.y, vi3 = p.y * q.x - p.x * q.y;
        const float P0 = 2.f * (wx * vr0 + wi * vi0);
        const float P1 = 2.f * (wx * vr1 + wi * vi1);
        const float P2 = 2.f * (wx * vr2 + wi * vi2);
        const float P3 = 2.f * (wx * vr3 + wi * vi3);
        const float Q0 = wx * c6 * vr0 - 2.f * wi * wz * vi0;
        const float Q1 = wx * c6 * vr1 - 2.f * wi * wz * vi1;
        const float Q2 = wx * c6 * vr2 - 2.f * wi * wz * vi2;
        const float Q3 = wx * c6 * vr3 - 2.f * wi * wz * vi3;
        const float C0 = -2.f * vr0, C1 = -2.f * vr1;
        const float C2 = -2.f * vr2, C3 = -2.f * vr3;
        const float D0 = -2.f * wz * vr0 + 4.f * wx * wi * vi0;
        const float D1 = -2.f * wz * vr1 + 4.f * wx * wi * vi1;
        const float D2 = -2.f * wz * vr2 + 4.f * wx * wi * vi2;
        const float D3 = -2.f * wz * vr3 + 4.f * wx * wi * vi3;
        s_t[n][0] = make_float4(-wisq, 0.5f * wz + wisq, 2.f * wz, P0);
        s_t[n][1] = make_float4(Q0, C0, D0, P1);
        s_t[n][2] = make_float4(Q1, C1, D1, P2);
        s_t[n][3] = make_float4(Q2, C2, D2, P3);
        s_t[n][4] = make_float4(Q3, C3, D3, wi);
    }
    __syncthreads();

    const int l = (chunk << 8) + tid;       // 0..4095
    // y = Im(z) = 2*tan(pi*l/L); rev = l/16384 (exact dyadic)
    const float rev = (float)l * 6.103515625e-5f;
    const float sn  = __builtin_amdgcn_sinf(rev);
    const float cn  = fmaxf(__builtin_amdgcn_cosf(rev), 4.3711388e-8f);
    const float y   = 2.0f * sn * __builtin_amdgcn_rcpf(cn);
    const float ysq = y * y;

    float re00 = 0.f, im00 = 0.f, re01 = 0.f, im01 = 0.f;
    float re10 = 0.f, im10 = 0.f, re11 = 0.f, im11 = 0.f;
    #pragma unroll 4
    for (int n = 0; n < NP; ++n) {
        const float4 t0 = s_t[n][0];
        const float4 t1 = s_t[n][1];
        const float4 t2 = s_t[n][2];
        const float4 t3 = s_t[n][3];
        const float4 t4 = s_t[n][4];
        const float g    = ysq + t0.x;                     // y^2 - wi^2
        const float tt   = ysq + t0.y;                     // y^2 + c4
        const float dd   = fmaf(g, g, t0.z * tt);          // d1*d2
        const float ir   = __builtin_amdgcn_rcpf(dd);
        const float gir  = g * ir;
        const float yir  = y * ir;
        const float gyir = g * yir;
        re00 = fmaf(t0.w, gir, fmaf(t1.x, ir, re00));
        im00 = fmaf(t1.y, gyir, fmaf(t1.z, yir, im00));
        re01 = fmaf(t1.w, gir, fmaf(t2.x, ir, re01));
        im01 = fmaf(t2.y, gyir, fmaf(t2.z, yir, im01));
        re10 = fmaf(t2.w, gir, fmaf(t3.x, ir, re10));
        im10 = fmaf(t3.y, gyir, fmaf(t3.z, yir, im10));
        re11 = fmaf(t3.w, gir, fmaf(t4.x, ir, re11));
        im11 = fmaf(t4.y, gyir, fmaf(t4.z, yir, im11));
    }

    // Woodbury, then bilinear factor
    {
        const float a00r = re00 * dt, a00i = im00 * dt;
        const float a01r = re01 * dt, a01i = im01 * dt;
        const float a10r = re10 * dt, a10i = im10 * dt;
        const float a11r = re11 * dt, a11i = im11 * dt;
        const float numr = a01r * a10r - a01i * a10i;
        const float numi = a01r * a10i + a01i * a10r;
        const float dwr = 1.f + a11r, dwi = a11i;
        const float idw = __builtin_amdgcn_rcpf(dwr * dwr + dwi * dwi);
        const float qr = (numr * dwr + numi * dwi) * idw;
        const float qi = (numi * dwr - numr * dwi) * idw;
        const float kfr = a00r - qr, kfi = a00i - qi;
        const float fi  = 0.5f * y;        // 2/(1+nodes) = 1 + i*tan(pi*l/L)
        float2* grow = (float2*)(spec + (size_t)h * LL);
        grow[l] = make_float2(kfr - kfi * fi, kfi + kfr * fi);
    }

    // ---- Nyquist bin l=4096: one pole per lane of wave 0 of chunk 15,
    //      same P/Q/C/D math at y4 (g^2 ~ 4.4e30, within fp32 range) ----
    if (chunk == 15 && tid < 64) {
        const int n = tid;
        const float4 t0 = s_t[n][0];
        const float4 t1 = s_t[n][1];
        const float4 t2 = s_t[n][2];
        const float4 t3 = s_t[n][3];
        const float4 t4 = s_t[n][4];
        // rev = 0.25 -> cos = 0 exactly; clamp reproduces reference's f32 z ~ 4.58e7
        const float y4 = 2.0f * __builtin_amdgcn_rcpf(4.3711388e-8f);
        const float y4sq = y4 * y4;
        const float g    = y4sq + t0.x;
        const float tt   = y4sq + t0.y;
        const float dd   = fmaf(g, g, t0.z * tt);
        const float ir   = __builtin_amdgcn_rcpf(dd);
        const float gir  = g * ir;
        const float yir  = y4 * ir;
        const float gyir = g * yir;
        float e0 = fmaf(t0.w, gir, t1.x * ir);
        float e1 = fmaf(t1.y, gyir, t1.z * yir);
        float e2 = fmaf(t1.w, gir, t2.x * ir);
        float e3 = fmaf(t2.y, gyir, t2.z * yir);
        float e4 = fmaf(t2.w, gir, t3.x * ir);
        float e5 = fmaf(t3.y, gyir, t3.z * yir);
        float e6 = fmaf(t3.w, gir, t4.x * ir);
        float e7 = fmaf(t4.y, gyir, t4.z * yir);
        #pragma unroll
        for (int m = 1; m < 64; m <<= 1) {
            e0 += __shfl_xor(e0, m);  e1 += __shfl_xor(e1, m);
            e2 += __shfl_xor(e2, m);  e3 += __shfl_xor(e3, m);
            e4 += __shfl_xor(e4, m);  e5 += __shfl_xor(e5, m);
            e6 += __shfl_xor(e6, m);  e7 += __shfl_xor(e7, m);
        }
        if (tid == 0) {
            const float a00r = e0 * dt, a00i = e1 * dt;
            const float a01r = e2 * dt, a01i = e3 * dt;
            const float a10r = e4 * dt, a10i = e5 * dt;
            const float a11r = e6 * dt, a11i = e7 * dt;
            const float numr = a01r * a10r - a01i * a10i;
            const float numi = a01r * a10i + a01i * a10r;
            const float dwr = 1.f + a11r, dwi = a11i;
            const float idw = __builtin_amdgcn_rcpf(dwr * dwr + dwi * dwi);
            const float qr = (numr * dwr + numi * dwi) * idw;
            const float qi = (numi * dwr - numr * dwi) * idw;
            const float kfr = a00r - qr, kfi = a00i - qi;
            const float fi  = 0.5f * y4;
            nyq[h] = make_float2(kfr - kfi * fi, kfi + kfr * fi);
        }
    }
}

// ---------------- Kernel B: pack + radix-4 Stockham iFFT + store -------------
__global__ __launch_bounds__(NTB)
void ifft_phase(float* __restrict__ io, const float2* __restrict__ nyq)
{
    __shared__ float2 sA[NHALF];
    __shared__ float2 sB[NHALF];

    const int h   = blockIdx.x;
    const int tid = threadIdx.x;
    float2* grow = (float2*)(io + (size_t)h * LL);

    // pack irfft(L) into complex iFFT(L/2), natural order:
    // Z[k] = (1/L)[(G[k]+conj(G[N-k])) + i*e^{+2pi i k/L}(G[k]-conj(G[N-k]))]
    #pragma unroll
    for (int ki = 0; ki < 4; ++ki) {
        const int k = tid + NTB * ki;
        const float2 Gk = grow[k];
        const float2 Gn = (k == 0) ? nyq[h] : grow[NHALF - k];
        const float Ar = Gk.x + Gn.x, Ai = Gk.y - Gn.y;
        const float Br = Gk.x - Gn.x, Bi = Gk.y + Gn.y;
        const float rev = (float)k * 1.220703125e-4f;   // k/8192
        const float cw = __builtin_amdgcn_cosf(rev);
        const float sw = __builtin_amdgcn_sinf(rev);
        const float sc = 1.0f / (float)LL;
        sA[k] = make_float2((Ar - cw * Bi - sw * Br) * sc,
                            (Ai + cw * Br - sw * Bi) * sc);
    }
    __syncthreads();

    // 6 radix-4 Stockham stages (inverse FFT, e^{+i} twiddles), ping-pong sA<->sB
    float2* pin  = sA;
    float2* pout = sB;
    #pragma unroll
    for (int s = 0; s < 6; ++s) {
        const int ls2 = 2 * s;
        const int Ls  = 1 << ls2;
        const int j   = tid;
        const int k   = j & (Ls - 1);
        const int tb  = k << (10 - ls2);
        const float fr = (float)tb * 2.44140625e-4f;    // tb/4096 revolutions
        const float c1 = __builtin_amdgcn_cosf(fr);
        const float s1 = __builtin_amdgcn_sinf(fr);
        const float c2 = __builtin_amdgcn_cosf(2.0f * fr);
        const float s2 = __builtin_amdgcn_sinf(2.0f * fr);
        const float c3 = __builtin_amdgcn_cosf(3.0f * fr);
        const float s3 = __builtin_amdgcn_sinf(3.0f * fr);
        float2 u0 = pin[j];
        float2 u1 = pin[j + 1024];
        float2 u2 = pin[j + 2048];
        float2 u3 = pin[j + 3072];
        float a, b;
        a = u1.x * c1 - u1.y * s1;  b = u1.x * s1 + u1.y * c1;  u1 = make_float2(a, b);
        a = u2.x * c2 - u2.y * s2;  b = u2.x * s2 + u2.y * c2;  u2 = make_float2(a, b);
        a = u3.x * c3 - u3.y * s3;  b = u3.x * s3 + u3.y * c3;  u3 = make_float2(a, b);
        const float t0r = u0.x + u2.x, t0i = u0.y + u2.y;
        const float t1r = u0.x - u2.x, t1i = u0.y - u2.y;
        const float t2r = u1.x + u3.x, t2i = u1.y + u3.y;
        const float t3r = u3.y - u1.y, t3i = u1.x - u3.x;   // i*(u1-u3)
        const int ob = ((j - k) << 2) + k;
        pout[ob]          = make_float2(t0r + t2r, t0i + t2i);
        pout[ob + Ls]     = make_float2(t1r + t3r, t1i + t3i);
        pout[ob + 2 * Ls] = make_float2(t0r - t2r, t0i - t2i);
        pout[ob + 3 * Ls] = make_float2(t1r - t3r, t1i - t3i);
        float2* tmp = pin; pin = pout; pout = tmp;
        __syncthreads();
    }

    // final data lands in sA; x[2j]=Re, x[2j+1]=Im -> coalesced float2 store
    #pragma unroll
    for (int ji = 0; ji < 4; ++ji) {
        const int j = tid + NTB * ji;
        grow[j] = sA[j];
    }
}

extern "C" void kernel_launch(void* const* d_in, const int* in_sizes, int n_in,
                              void* d_out, int out_size, void* d_ws, size_t ws_size,
                              hipStream_t stream) {
    const float* w   = (const float*)d_in[0];
    const float* p   = (const float*)d_in[1];
    const float* q   = (const float*)d_in[2];
    const float* B   = (const float*)d_in[3];
    const float* C   = (const float*)d_in[4];
    const float* ldt = (const float*)d_in[5];
    float*  spec = (float*)d_out;          // spectrum staged in-place in d_out
    float2* nyq  = (float2*)d_ws;          // 256 * 8 B Nyquist bins

    dim3 gridA(16, NUM_H);
    cauchy_phase<<<gridA, NTA, 0, stream>>>(w, p, q, B, C, ldt, spec, nyq);
    ifft_phase<<<NUM_H, NTB, 0, stream>>>(spec, nyq);
}

// Round 16
// 45.930 us; speedup vs baseline: 1.9720x; 1.9720x over previous
//
#include <hip/hip_runtime.h>
#include <math.h>

#define NUM_H 256
#define NP    64        // poles per h
#define LL    8192      // sequence length
#define NHALF 4096      // LL/2 (complex FFT size)
#define NTA   256       // threads, Cauchy kernel
#define NTB   1024      // threads, FFT kernel

typedef float v2f __attribute__((ext_vector_type(2)));

// v_sin_f32 / v_cos_f32 take input in REVOLUTIONS (D = sin(S0 * 2pi)).

// P/Q strength-reduced per-pole coefficients (r14-proven, ref-checked):
//   g = y^2 - wi^2; dd = d1*d2 = g^2 + (c2*y^2 + c1); ir = 1/dd
//   real contrib = P*g*ir + Q*ir;  imag contrib = C*g*y*ir + D*y*ir
//   c1 = wz^2 + 2wz*wi^2; c2 = 2wz; c6 = 4wi^2 + 2wz; wz = wr^2; wx = -wr
//   P = 2(wx*vr + wi*vi);  Q = wx*c6*vr - 2wi*wz*vi
//   C = -2vr;              D = -2wz*vr + 4wx*wi*vi
// Table: 20 v2f per pole-pair, field i at float offset 2i+o (o = pole parity):
//   f[0]=nwisq f[1]=c1 f[2]=c2 f[3]=wi(pad)  f[4+4j..7+4j]={P,Q,C,D}_j j=0..3
//
// NOTE: NO pointer-indexing across asm-tied locals anywhere (r8/r15 600s
// timeouts both contained `v2f* acc = cond ? &b0 : &a0` epilogues; the
// passing kernels r12/r13 did not — epilogues here are written out per bin).

struct PolePairPQ { v2f fld[20]; };

// ---------------- Kernel A: Cauchy sum + Woodbury -> spectrum ----------------
__global__ __launch_bounds__(NTA)
void cauchy_phase(const float* __restrict__ w_ri,
                  const float* __restrict__ p_ri,
                  const float* __restrict__ q_ri,
                  const float* __restrict__ B_ri,
                  const float* __restrict__ C_ri,
                  const float* __restrict__ log_dt,
                  float*       __restrict__ spec,   // (H, 4096) float2 rows (= d_out)
                  float2*      __restrict__ nyq)    // (H,) Nyquist bins (= d_ws)
{
    __shared__ PolePairPQ s_pp[NP / 2];

    const int h     = blockIdx.y;
    const int chunk = blockIdx.x;      // 8 chunks of 256 low bins
    const int tid   = threadIdx.x;
    const float dt  = expf(log_dt[h]);

    if (tid < NP) {
        const int n = tid;
        const int k = n >> 1, o = n & 1;
        const float2 w = ((const float2*)w_ri)[h * NP + n];
        const float2 p = ((const float2*)p_ri)[h * NP + n];
        const float2 q = ((const float2*)q_ri)[h * NP + n];
        const float2 B = ((const float2*)B_ri)[h * NP + n];
        const float2 C = ((const float2*)C_ri)[h * NP + n];
        const float wr = w.x * dt, wi = w.y * dt;
        const float wz = wr * wr, wisq = wi * wi, wx = -wr;
        const float c6 = 4.f * wisq + 2.f * wz;
        const float vrs[4] = {B.x * C.x + B.y * C.y, p.x * C.x + p.y * C.y,
                              B.x * q.x + B.y * q.y, p.x * q.x + p.y * q.y};
        const float vis[4] = {B.y * C.x - B.x * C.y, p.y * C.x - p.x * C.y,
                              B.y * q.x - B.x * q.y, p.y * q.x - p.x * q.y};
        float* base = (float*)&s_pp[k];
        base[0 + o] = -wisq;                        // nwisq
        base[2 + o] = wz * wz + 2.f * wz * wisq;    // c1
        base[4 + o] = 2.f * wz;                     // c2
        base[6 + o] = wi;                           // pad/wi
        #pragma unroll
        for (int j = 0; j < 4; ++j) {
            base[(8  + 8 * j) + o] = 2.f * (wx * vrs[j] + wi * vis[j]);           // P
            base[(10 + 8 * j) + o] = wx * c6 * vrs[j] - 2.f * wi * wz * vis[j];   // Q
            base[(12 + 8 * j) + o] = -2.f * vrs[j];                               // C
            base[(14 + 8 * j) + o] = -2.f * wz * vrs[j] + 4.f * wx * wi * vis[j]; // D
        }
    }
    __syncthreads();

    const int lA = (chunk << 8) + tid;       // 0..2047
    const int lB = lA + 2048;                // 2048..4095
    // y = Im(z) = 2*tan(pi*l/L); rev = l/16384 (exact dyadic)
    float yS[2];
    #pragma unroll
    for (int b = 0; b < 2; ++b) {
        const int l = lA + (b << 11);
        const float rev = (float)l * 6.103515625e-5f;
        const float sn  = __builtin_amdgcn_sinf(rev);
        const float cn  = fmaxf(__builtin_amdgcn_cosf(rev), 4.3711388e-8f);
        yS[b] = 2.0f * sn * __builtin_amdgcn_rcpf(cn);
    }
    const float yAv = yS[0], yBv = yS[1];
    const v2f yAsq = {yAv * yAv, yAv * yAv};
    const v2f yAsp = {yAv, yAv};
    const v2f yBsq = {yBv * yBv, yBv * yBv};
    const v2f yBsp = {yBv, yBv};

    v2f rA0 = 0.f, iA0 = 0.f, rA1 = 0.f, iA1 = 0.f;
    v2f rA2 = 0.f, iA2 = 0.f, rA3 = 0.f, iA3 = 0.f;
    v2f rB0 = 0.f, iB0 = 0.f, rB1 = 0.f, iB1 = 0.f;
    v2f rB2 = 0.f, iB2 = 0.f, rB3 = 0.f, iB3 = 0.f;
    #pragma unroll 1
    for (int k = 0; k < NP / 2; ++k) {
        const v2f* f = s_pp[k].fld;
        const v2f nwisq = f[0], c1 = f[1], c2 = f[2];
        const v2f P0 = f[4],  Q0 = f[5],  C0 = f[6],  D0 = f[7];
        const v2f P1 = f[8],  Q1 = f[9],  C1 = f[10], D1 = f[11];
        const v2f P2 = f[12], Q2 = f[13], C2 = f[14], D2 = f[15];
        const v2f P3 = f[16], Q3 = f[17], C3 = f[18], D3 = f[19];

        // ---- bin A: denominator + basis (r13-proven block shapes) ----
        v2f gA, inA, ddA;
        asm("v_pk_add_f32 %0, %3, %4\n\t"        // g = y^2 + (-wi^2)
            "v_pk_fma_f32 %1, %5, %3, %6\n\t"    // inner = c2*y^2 + c1
            "v_pk_fma_f32 %2, %0, %0, %1"        // dd = g*g + inner
            : "=&v"(gA), "=&v"(inA), "=&v"(ddA)
            : "v"(yAsq), "v"(nwisq), "v"(c2), "v"(c1));
        const v2f irA = {__builtin_amdgcn_rcpf(ddA.x), __builtin_amdgcn_rcpf(ddA.y)};
        v2f girA, yirA, gyirA;
        asm("v_pk_mul_f32 %0, %3, %4\n\t"        // gir  = g * ir
            "v_pk_mul_f32 %1, %5, %4\n\t"        // yir  = y * ir
            "v_pk_mul_f32 %2, %3, %1"            // gyir = g * yir
            : "=&v"(girA), "=&v"(yirA), "=&v"(gyirA)
            : "v"(gA), "v"(irA), "v"(yAsp));

        // ---- bin B: denominator + basis ----
        v2f gB, inB, ddB;
        asm("v_pk_add_f32 %0, %3, %4\n\t"
            "v_pk_fma_f32 %1, %5, %3, %6\n\t"
            "v_pk_fma_f32 %2, %0, %0, %1"
            : "=&v"(gB), "=&v"(inB), "=&v"(ddB)
            : "v"(yBsq), "v"(nwisq), "v"(c2), "v"(c1));
        const v2f irB = {__builtin_amdgcn_rcpf(ddB.x), __builtin_amdgcn_rcpf(ddB.y)};
        v2f girB, yirB, gyirB;
        asm("v_pk_mul_f32 %0, %3, %4\n\t"
            "v_pk_mul_f32 %1, %5, %4\n\t"
            "v_pk_mul_f32 %2, %3, %1"
            : "=&v"(girB), "=&v"(yirB), "=&v"(gyirB)
            : "v"(gB), "v"(irB), "v"(yBsp));

        // ---- accumulate bin A (one 16-inst block, 8 tied outputs) ----
        asm("v_pk_fma_f32 %0, %12, %8, %0\n\t"   // r0 += P0*gir
            "v_pk_fma_f32 %0, %13, %9, %0\n\t"   // r0 += Q0*ir
            "v_pk_fma_f32 %1, %14, %10, %1\n\t"  // i0 += C0*gyir
            "v_pk_fma_f32 %1, %15, %11, %1\n\t"  // i0 += D0*yir
            "v_pk_fma_f32 %2, %16, %8, %2\n\t"
            "v_pk_fma_f32 %2, %17, %9, %2\n\t"
            "v_pk_fma_f32 %3, %18, %10, %3\n\t"
            "v_pk_fma_f32 %3, %19, %11, %3\n\t"
            "v_pk_fma_f32 %4, %20, %8, %4\n\t"
            "v_pk_fma_f32 %4, %21, %9, %4\n\t"
            "v_pk_fma_f32 %5, %22, %10, %5\n\t"
            "v_pk_fma_f32 %5, %23, %11, %5\n\t"
            "v_pk_fma_f32 %6, %24, %8, %6\n\t"
            "v_pk_fma_f32 %6, %25, %9, %6\n\t"
            "v_pk_fma_f32 %7, %26, %10, %7\n\t"
            "v_pk_fma_f32 %7, %27, %11, %7"
            : "+v"(rA0), "+v"(iA0), "+v"(rA1), "+v"(iA1),
              "+v"(rA2), "+v"(iA2), "+v"(rA3), "+v"(iA3)
            : "v"(girA), "v"(irA), "v"(gyirA), "v"(yirA),
              "v"(P0), "v"(Q0), "v"(C0), "v"(D0),
              "v"(P1), "v"(Q1), "v"(C1), "v"(D1),
              "v"(P2), "v"(Q2), "v"(C2), "v"(D2),
              "v"(P3), "v"(Q3), "v"(C3), "v"(D3));

        // ---- accumulate bin B ----
        asm("v_pk_fma_f32 %0, %12, %8, %0\n\t"
            "v_pk_fma_f32 %0, %13, %9, %0\n\t"
            "v_pk_fma_f32 %1, %14, %10, %1\n\t"
            "v_pk_fma_f32 %1, %15, %11, %1\n\t"
            "v_pk_fma_f32 %2, %16, %8, %2\n\t"
            "v_pk_fma_f32 %2, %17, %9, %2\n\t"
            "v_pk_fma_f32 %3, %18, %10, %3\n\t"
            "v_pk_fma_f32 %3, %19, %11, %3\n\t"
            "v_pk_fma_f32 %4, %20, %8, %4\n\t"
            "v_pk_fma_f32 %4, %21, %9, %4\n\t"
            "v_pk_fma_f32 %5, %22, %10, %5\n\t"
            "v_pk_fma_f32 %5, %23, %11, %5\n\t"
            "v_pk_fma_f32 %6, %24, %8, %6\n\t"
            "v_pk_fma_f32 %6, %25, %9, %6\n\t"
            "v_pk_fma_f32 %7, %26, %10, %7\n\t"
            "v_pk_fma_f32 %7, %27, %11, %7"
            : "+v"(rB0), "+v"(iB0), "+v"(rB1), "+v"(iB1),
              "+v"(rB2), "+v"(iB2), "+v"(rB3), "+v"(iB3)
            : "v"(girB), "v"(irB), "v"(gyirB), "v"(yirB),
              "v"(P0), "v"(Q0), "v"(C0), "v"(D0),
              "v"(P1), "v"(Q1), "v"(C1), "v"(D1),
              "v"(P2), "v"(Q2), "v"(C2), "v"(D2),
              "v"(P3), "v"(Q3), "v"(C3), "v"(D3));
    }

    // horizontal add, Woodbury, bilinear — written out per bin (NO pointers)
    float2* grow = (float2*)(spec + (size_t)h * LL);
    {
        const float a00r = (rA0.x + rA0.y) * dt, a00i = (iA0.x + iA0.y) * dt;
        const float a01r = (rA1.x + rA1.y) * dt, a01i = (iA1.x + iA1.y) * dt;
        const float a10r = (rA2.x + rA2.y) * dt, a10i = (iA2.x + iA2.y) * dt;
        const float a11r = (rA3.x + rA3.y) * dt, a11i = (iA3.x + iA3.y) * dt;
        const float numr = a01r * a10r - a01i * a10i;
        const float numi = a01r * a10i + a01i * a10r;
        const float dwr = 1.f + a11r, dwi = a11i;
        const float idw = __builtin_amdgcn_rcpf(dwr * dwr + dwi * dwi);
        const float qr = (numr * dwr + numi * dwi) * idw;
        const float qi = (numi * dwr - numr * dwi) * idw;
        const float kfr = a00r - qr, kfi = a00i - qi;
        const float fi  = 0.5f * yAv;      // 2/(1+nodes) = 1 + i*tan(pi*l/L)
        grow[lA] = make_float2(kfr - kfi * fi, kfi + kfr * fi);
    }
    {
        const float a00r = (rB0.x + rB0.y) * dt, a00i = (iB0.x + iB0.y) * dt;
        const float a01r = (rB1.x + rB1.y) * dt, a01i = (iB1.x + iB1.y) * dt;
        const float a10r = (rB2.x + rB2.y) * dt, a10i = (iB2.x + iB2.y) * dt;
        const float a11r = (rB3.x + rB3.y) * dt, a11i = (iB3.x + iB3.y) * dt;
        const float numr = a01r * a10r - a01i * a10i;
        const float numi = a01r * a10i + a01i * a10r;
        const float dwr = 1.f + a11r, dwi = a11i;
        const float idw = __builtin_amdgcn_rcpf(dwr * dwr + dwi * dwi);
        const float qr = (numr * dwr + numi * dwi) * idw;
        const float qi = (numi * dwr - numr * dwi) * idw;
        const float kfr = a00r - qr, kfi = a00i - qi;
        const float fi  = 0.5f * yBv;
        grow[lB] = make_float2(kfr - kfi * fi, kfi + kfr * fi);
    }

    // ---- Nyquist bin l=4096 (r14-proven P/Q path), wave 0 of chunk 7 ----
    if (chunk == 7 && tid < 64) {
        const int n = tid;
        const int k = n >> 1, o = n & 1;
        const float* base = (const float*)&s_pp[k];
        const float nwisq_s = base[0 + o];
        const float c1_s    = base[2 + o];
        const float c2_s    = base[4 + o];
        // rev = 0.25 -> cos = 0 exactly; clamp reproduces reference's f32 z ~ 4.58e7
        const float y4 = 2.0f * __builtin_amdgcn_rcpf(4.3711388e-8f);
        const float y4sq = y4 * y4;
        const float g  = y4sq + nwisq_s;
        const float dd = fmaf(g, g, fmaf(c2_s, y4sq, c1_s));
        const float ir = __builtin_amdgcn_rcpf(dd);
        const float gir = g * ir, yir = y4 * ir, gyir = g * yir;
        float e[8];
        #pragma unroll
        for (int j = 0; j < 4; ++j) {
            const float P = base[(8  + 8 * j) + o];
            const float Q = base[(10 + 8 * j) + o];
            const float Cc = base[(12 + 8 * j) + o];
            const float D = base[(14 + 8 * j) + o];
            e[2 * j]     = fmaf(P, gir, Q * ir);
            e[2 * j + 1] = fmaf(Cc, gyir, D * yir);
        }
        #pragma unroll
        for (int m = 1; m < 64; m <<= 1) {
            #pragma unroll
            for (int t = 0; t < 8; ++t) e[t] += __shfl_xor(e[t], m);
        }
        if (tid == 0) {
            const float a00r = e[0] * dt, a00i = e[1] * dt;
            const float a01r = e[2] * dt, a01i = e[3] * dt;
            const float a10r = e[4] * dt, a10i = e[5] * dt;
            const float a11r = e[6] * dt, a11i = e[7] * dt;
            const float numr = a01r * a10r - a01i * a10i;
            const float numi = a01r * a10i + a01i * a10r;
            const float dwr = 1.f + a11r, dwi = a11i;
            const float idw = __builtin_amdgcn_rcpf(dwr * dwr + dwi * dwi);
            const float qr = (numr * dwr + numi * dwi) * idw;
            const float qi = (numi * dwr - numr * dwi) * idw;
            const float kfr = a00r - qr, kfi = a00i - qi;
            const float fi  = 0.5f * y4;
            nyq[h] = make_float2(kfr - kfi * fi, kfi + kfr * fi);
        }
    }
}

// ---------------- Kernel B: pack + radix-4 Stockham iFFT + store -------------
__global__ __launch_bounds__(NTB)
void ifft_phase(float* __restrict__ io, const float2* __restrict__ nyq)
{
    __shared__ float2 sA[NHALF];
    __shared__ float2 sB[NHALF];

    const int h   = blockIdx.x;
    const int tid = threadIdx.x;
    float2* grow = (float2*)(io + (size_t)h * LL);

    // pack irfft(L) into complex iFFT(L/2), natural order:
    // Z[k] = (1/L)[(G[k]+conj(G[N-k])) + i*e^{+2pi i k/L}(G[k]-conj(G[N-k]))]
    #pragma unroll
    for (int ki = 0; ki < 4; ++ki) {
        const int k = tid + NTB * ki;
        const float2 Gk = grow[k];
        const float2 Gn = (k == 0) ? nyq[h] : grow[NHALF - k];
        const float Ar = Gk.x + Gn.x, Ai = Gk.y - Gn.y;
        const float Br = Gk.x - Gn.x, Bi = Gk.y + Gn.y;
        const float rev = (float)k * 1.220703125e-4f;   // k/8192
        const float cw = __builtin_amdgcn_cosf(rev);
        const float sw = __builtin_amdgcn_sinf(rev);
        const float sc = 1.0f / (float)LL;
        sA[k] = make_float2((Ar - cw * Bi - sw * Br) * sc,
                            (Ai + cw * Br - sw * Bi) * sc);
    }
    __syncthreads();

    // 6 radix-4 Stockham stages (inverse FFT, e^{+i} twiddles), ping-pong sA<->sB
    float2* pin  = sA;
    float2* pout = sB;
    #pragma unroll
    for (int s = 0; s < 6; ++s) {
        const int ls2 = 2 * s;
        const int Ls  = 1 << ls2;
        const int j   = tid;
        const int k   = j & (Ls - 1);
        const int tb  = k << (10 - ls2);
        const float fr = (float)tb * 2.44140625e-4f;    // tb/4096 revolutions
        const float c1 = __builtin_amdgcn_cosf(fr);
        const float s1 = __builtin_amdgcn_sinf(fr);
        const float c2 = __builtin_amdgcn_cosf(2.0f * fr);
        const float s2 = __builtin_amdgcn_sinf(2.0f * fr);
        const float c3 = __builtin_amdgcn_cosf(3.0f * fr);
        const float s3 = __builtin_amdgcn_sinf(3.0f * fr);
        float2 u0 = pin[j];
        float2 u1 = pin[j + 1024];
        float2 u2 = pin[j + 2048];
        float2 u3 = pin[j + 3072];
        float a, b;
        a = u1.x * c1 - u1.y * s1;  b = u1.x * s1 + u1.y * c1;  u1 = make_float2(a, b);
        a = u2.x * c2 - u2.y * s2;  b = u2.x * s2 + u2.y * c2;  u2 = make_float2(a, b);
        a = u3.x * c3 - u3.y * s3;  b = u3.x * s3 + u3.y * c3;  u3 = make_float2(a, b);
        const float t0r = u0.x + u2.x, t0i = u0.y + u2.y;
        const float t1r = u0.x - u2.x, t1i = u0.y - u2.y;
        const float t2r = u1.x + u3.x, t2i = u1.y + u3.y;
        const float t3r = u3.y - u1.y, t3i = u1.x - u3.x;   // i*(u1-u3)
        const int ob = ((j - k) << 2) + k;
        pout[ob]          = make_float2(t0r + t2r, t0i + t2i);
        pout[ob + Ls]     = make_float2(t1r + t3r, t1i + t3i);
        pout[ob + 2 * Ls] = make_float2(t0r - t2r, t0i - t2i);
        pout[ob + 3 * Ls] = make_float2(t1r - t3r, t1i - t3i);
        float2* tmp = pin; pin = pout; pout = tmp;
        __syncthreads();
    }

    // final data lands in sA; x[2j]=Re, x[2j+1]=Im -> coalesced float2 store
    #pragma unroll
    for (int ji = 0; ji < 4; ++ji) {
        const int j = tid + NTB * ji;
        grow[j] = sA[j];
    }
}

extern "C" void kernel_launch(void* const* d_in, const int* in_sizes, int n_in,
                              void* d_out, int out_size, void* d_ws, size_t ws_size,
                              hipStream_t stream) {
    const float* w   = (const float*)d_in[0];
    const float* p   = (const float*)d_in[1];
    const float* q   = (const float*)d_in[2];
    const float* B   = (const float*)d_in[3];
    const float* C   = (const float*)d_in[4];
    const float* ldt = (const float*)d_in[5];
    float*  spec = (float*)d_out;          // spectrum staged in-place in d_out
    float2* nyq  = (float2*)d_ws;          // 256 * 8 B Nyquist bins

    dim3 gridA(8, NUM_H);
    cauchy_phase<<<gridA, NTA, 0, stream>>>(w, p, q, B, C, ldt, spec, nyq);
    ifft_phase<<<NUM_H, NTB, 0, stream>>>(spec, nyq);
}

// Round 18
// 43.777 us; speedup vs baseline: 2.0690x; 1.0492x over previous
//
#include <hip/hip_runtime.h>
#include <math.h>

#define NUM_H 256
#define NP    64        // poles per h
#define LL    8192      // sequence length
#define NHALF 4096      // LL/2 (complex FFT size)
#define NTA   256       // threads, Cauchy kernel
#define NTB   1024      // threads, FFT kernel

typedef float v2f __attribute__((ext_vector_type(2)));

// v_sin_f32 / v_cos_f32 take input in REVOLUTIONS (D = sin(S0 * 2pi)).

// P/Q strength-reduced per-pole coefficients (r14/r16-proven):
//   g = y^2 - wi^2; dd = d1*d2 = g^2 + (c2*y^2 + c1); ir = 1/dd
//   real contrib = P*g*ir + Q*ir
//   imag contrib = y * (C*g*ir + D*ir)    [y hoisted out of the pole sum]
//   c1 = wz^2 + 2wz*wi^2; c2 = 2wz; c6 = 4wi^2 + 2wz; wz = wr^2; wx = -wr
//   P = 2(wx*vr + wi*vi);  Q = wx*c6*vr - 2wi*wz*vi
//   C = -2vr;              D = -2wz*vr + 4wx*wi*vi
// Table: 20 v2f per pole-pair, field i at float offset 2i+o (o = pole parity):
//   f[0]=nwisq f[1]=c1 f[2]=c2 f[3]=wi(pad)  f[4+4j..7+4j]={P,Q,C,D}_j j=0..3
//
// HARD RULES (from failures): NO pointer-indexing across asm-tied locals
// (r8/r15 compile timeouts); NO #pragma unroll >1 around the tied-asm loop
// (r11/r17 silent miscompiles — tied-operand spill under unroll-2 pressure).
// Accumulate blocks ordered so each accumulator is touched once per 8-inst
// pass (removes back-to-back same-register FMA stalls of r16).

struct PolePairPQ { v2f fld[20]; };

// ---------------- Kernel A: Cauchy sum + Woodbury -> spectrum ----------------
__global__ __launch_bounds__(NTA)
void cauchy_phase(const float* __restrict__ w_ri,
                  const float* __restrict__ p_ri,
                  const float* __restrict__ q_ri,
                  const float* __restrict__ B_ri,
                  const float* __restrict__ C_ri,
                  const float* __restrict__ log_dt,
                  float*       __restrict__ spec,   // (H, 4096) float2 rows (= d_out)
                  float2*      __restrict__ nyq)    // (H,) Nyquist bins (= d_ws)
{
    __shared__ PolePairPQ s_pp[NP / 2];

    const int h     = blockIdx.y;
    const int chunk = blockIdx.x;      // 8 chunks of 256 low bins
    const int tid   = threadIdx.x;
    const float dt  = expf(log_dt[h]);

    if (tid < NP) {
        const int n = tid;
        const int k = n >> 1, o = n & 1;
        const float2 w = ((const float2*)w_ri)[h * NP + n];
        const float2 p = ((const float2*)p_ri)[h * NP + n];
        const float2 q = ((const float2*)q_ri)[h * NP + n];
        const float2 B = ((const float2*)B_ri)[h * NP + n];
        const float2 C = ((const float2*)C_ri)[h * NP + n];
        const float wr = w.x * dt, wi = w.y * dt;
        const float wz = wr * wr, wisq = wi * wi, wx = -wr;
        const float c6 = 4.f * wisq + 2.f * wz;
        const float vrs[4] = {B.x * C.x + B.y * C.y, p.x * C.x + p.y * C.y,
                              B.x * q.x + B.y * q.y, p.x * q.x + p.y * q.y};
        const float vis[4] = {B.y * C.x - B.x * C.y, p.y * C.x - p.x * C.y,
                              B.y * q.x - B.x * q.y, p.y * q.x - p.x * q.y};
        float* base = (float*)&s_pp[k];
        base[0 + o] = -wisq;                        // nwisq
        base[2 + o] = wz * wz + 2.f * wz * wisq;    // c1
        base[4 + o] = 2.f * wz;                     // c2
        base[6 + o] = wi;                           // pad/wi
        #pragma unroll
        for (int j = 0; j < 4; ++j) {
            base[(8  + 8 * j) + o] = 2.f * (wx * vrs[j] + wi * vis[j]);           // P
            base[(10 + 8 * j) + o] = wx * c6 * vrs[j] - 2.f * wi * wz * vis[j];   // Q
            base[(12 + 8 * j) + o] = -2.f * vrs[j];                               // C
            base[(14 + 8 * j) + o] = -2.f * wz * vrs[j] + 4.f * wx * wi * vis[j]; // D
        }
    }
    __syncthreads();

    const int lA = (chunk << 8) + tid;       // 0..2047
    const int lB = lA + 2048;                // 2048..4095
    // y = Im(z) = 2*tan(pi*l/L); rev = l/16384 (exact dyadic)
    float yS[2];
    #pragma unroll
    for (int b = 0; b < 2; ++b) {
        const int l = lA + (b << 11);
        const float rev = (float)l * 6.103515625e-5f;
        const float sn  = __builtin_amdgcn_sinf(rev);
        const float cn  = fmaxf(__builtin_amdgcn_cosf(rev), 4.3711388e-8f);
        yS[b] = 2.0f * sn * __builtin_amdgcn_rcpf(cn);
    }
    const float yAv = yS[0], yBv = yS[1];
    const v2f yAsq = {yAv * yAv, yAv * yAv};
    const v2f yBsq = {yBv * yBv, yBv * yBv};

    v2f rA0 = 0.f, iA0 = 0.f, rA1 = 0.f, iA1 = 0.f;
    v2f rA2 = 0.f, iA2 = 0.f, rA3 = 0.f, iA3 = 0.f;
    v2f rB0 = 0.f, iB0 = 0.f, rB1 = 0.f, iB1 = 0.f;
    v2f rB2 = 0.f, iB2 = 0.f, rB3 = 0.f, iB3 = 0.f;
    #pragma unroll 1
    for (int k = 0; k < NP / 2; ++k) {
        const v2f* f = s_pp[k].fld;
        const v2f nwisq = f[0], c1 = f[1], c2 = f[2];
        const v2f P0 = f[4],  Q0 = f[5],  C0 = f[6],  D0 = f[7];
        const v2f P1 = f[8],  Q1 = f[9],  C1 = f[10], D1 = f[11];
        const v2f P2 = f[12], Q2 = f[13], C2 = f[14], D2 = f[15];
        const v2f P3 = f[16], Q3 = f[17], C3 = f[18], D3 = f[19];

        // ---- bin A: denominator + gir basis ----
        v2f gA, inA, ddA;
        asm("v_pk_add_f32 %0, %3, %4\n\t"        // g = y^2 + (-wi^2)
            "v_pk_fma_f32 %1, %5, %3, %6\n\t"    // inner = c2*y^2 + c1
            "v_pk_fma_f32 %2, %0, %0, %1"        // dd = g*g + inner
            : "=&v"(gA), "=&v"(inA), "=&v"(ddA)
            : "v"(yAsq), "v"(nwisq), "v"(c2), "v"(c1));
        const v2f irA = {__builtin_amdgcn_rcpf(ddA.x), __builtin_amdgcn_rcpf(ddA.y)};
        v2f girA;
        asm("v_pk_mul_f32 %0, %1, %2"            // gir = g * ir
            : "=&v"(girA) : "v"(gA), "v"(irA));

        // ---- bin B: denominator + gir basis ----
        v2f gB, inB, ddB;
        asm("v_pk_add_f32 %0, %3, %4\n\t"
            "v_pk_fma_f32 %1, %5, %3, %6\n\t"
            "v_pk_fma_f32 %2, %0, %0, %1"
            : "=&v"(gB), "=&v"(inB), "=&v"(ddB)
            : "v"(yBsq), "v"(nwisq), "v"(c2), "v"(c1));
        const v2f irB = {__builtin_amdgcn_rcpf(ddB.x), __builtin_amdgcn_rcpf(ddB.y)};
        v2f girB;
        asm("v_pk_mul_f32 %0, %1, %2"
            : "=&v"(girB) : "v"(gB), "v"(irB));

        // ---- accumulate bin A: pass 1 = all accums x gir, pass 2 = x ir ----
        asm("v_pk_fma_f32 %0, %10, %8, %0\n\t"   // r0 += P0*gir
            "v_pk_fma_f32 %1, %12, %8, %1\n\t"   // i0 += C0*gir
            "v_pk_fma_f32 %2, %14, %8, %2\n\t"   // r1 += P1*gir
            "v_pk_fma_f32 %3, %16, %8, %3\n\t"   // i1 += C1*gir
            "v_pk_fma_f32 %4, %18, %8, %4\n\t"   // r2 += P2*gir
            "v_pk_fma_f32 %5, %20, %8, %5\n\t"   // i2 += C2*gir
            "v_pk_fma_f32 %6, %22, %8, %6\n\t"   // r3 += P3*gir
            "v_pk_fma_f32 %7, %24, %8, %7\n\t"   // i3 += C3*gir
            "v_pk_fma_f32 %0, %11, %9, %0\n\t"   // r0 += Q0*ir
            "v_pk_fma_f32 %1, %13, %9, %1\n\t"   // i0 += D0*ir
            "v_pk_fma_f32 %2, %15, %9, %2\n\t"
            "v_pk_fma_f32 %3, %17, %9, %3\n\t"
            "v_pk_fma_f32 %4, %19, %9, %4\n\t"
            "v_pk_fma_f32 %5, %21, %9, %5\n\t"
            "v_pk_fma_f32 %6, %23, %9, %6\n\t"
            "v_pk_fma_f32 %7, %25, %9, %7"
            : "+v"(rA0), "+v"(iA0), "+v"(rA1), "+v"(iA1),
              "+v"(rA2), "+v"(iA2), "+v"(rA3), "+v"(iA3)
            : "v"(girA), "v"(irA),
              "v"(P0), "v"(Q0), "v"(C0), "v"(D0),
              "v"(P1), "v"(Q1), "v"(C1), "v"(D1),
              "v"(P2), "v"(Q2), "v"(C2), "v"(D2),
              "v"(P3), "v"(Q3), "v"(C3), "v"(D3));

        // ---- accumulate bin B ----
        asm("v_pk_fma_f32 %0, %10, %8, %0\n\t"
            "v_pk_fma_f32 %1, %12, %8, %1\n\t"
            "v_pk_fma_f32 %2, %14, %8, %2\n\t"
            "v_pk_fma_f32 %3, %16, %8, %3\n\t"
            "v_pk_fma_f32 %4, %18, %8, %4\n\t"
            "v_pk_fma_f32 %5, %20, %8, %5\n\t"
            "v_pk_fma_f32 %6, %22, %8, %6\n\t"
            "v_pk_fma_f32 %7, %24, %8, %7\n\t"
            "v_pk_fma_f32 %0, %11, %9, %0\n\t"
            "v_pk_fma_f32 %1, %13, %9, %1\n\t"
            "v_pk_fma_f32 %2, %15, %9, %2\n\t"
            "v_pk_fma_f32 %3, %17, %9, %3\n\t"
            "v_pk_fma_f32 %4, %19, %9, %4\n\t"
            "v_pk_fma_f32 %5, %21, %9, %5\n\t"
            "v_pk_fma_f32 %6, %23, %9, %6\n\t"
            "v_pk_fma_f32 %7, %25, %9, %7"
            : "+v"(rB0), "+v"(iB0), "+v"(rB1), "+v"(iB1),
              "+v"(rB2), "+v"(iB2), "+v"(rB3), "+v"(iB3)
            : "v"(girB), "v"(irB),
              "v"(P0), "v"(Q0), "v"(C0), "v"(D0),
              "v"(P1), "v"(Q1), "v"(C1), "v"(D1),
              "v"(P2), "v"(Q2), "v"(C2), "v"(D2),
              "v"(P3), "v"(Q3), "v"(C3), "v"(D3));
    }

    // horizontal add, apply dt (and y to imag), Woodbury, bilinear — per bin
    float2* grow = (float2*)(spec + (size_t)h * LL);
    {
        const float dty = dt * yAv;
        const float a00r = (rA0.x + rA0.y) * dt, a00i = (iA0.x + iA0.y) * dty;
        const float a01r = (rA1.x + rA1.y) * dt, a01i = (iA1.x + iA1.y) * dty;
        const float a10r = (rA2.x + rA2.y) * dt, a10i = (iA2.x + iA2.y) * dty;
        const float a11r = (rA3.x + rA3.y) * dt, a11i = (iA3.x + iA3.y) * dty;
        const float numr = a01r * a10r - a01i * a10i;
        const float numi = a01r * a10i + a01i * a10r;
        const float dwr = 1.f + a11r, dwi = a11i;
        const float idw = __builtin_amdgcn_rcpf(dwr * dwr + dwi * dwi);
        const float qr = (numr * dwr + numi * dwi) * idw;
        const float qi = (numi * dwr - numr * dwi) * idw;
        const float kfr = a00r - qr, kfi = a00i - qi;
        const float fi  = 0.5f * yAv;      // 2/(1+nodes) = 1 + i*tan(pi*l/L)
        grow[lA] = make_float2(kfr - kfi * fi, kfi + kfr * fi);
    }
    {
        const float dty = dt * yBv;
        const float a00r = (rB0.x + rB0.y) * dt, a00i = (iB0.x + iB0.y) * dty;
        const float a01r = (rB1.x + rB1.y) * dt, a01i = (iB1.x + iB1.y) * dty;
        const float a10r = (rB2.x + rB2.y) * dt, a10i = (iB2.x + iB2.y) * dty;
        const float a11r = (rB3.x + rB3.y) * dt, a11i = (iB3.x + iB3.y) * dty;
        const float numr = a01r * a10r - a01i * a10i;
        const float numi = a01r * a10i + a01i * a10r;
        const float dwr = 1.f + a11r, dwi = a11i;
        const float idw = __builtin_amdgcn_rcpf(dwr * dwr + dwi * dwi);
        const float qr = (numr * dwr + numi * dwi) * idw;
        const float qi = (numi * dwr - numr * dwi) * idw;
        const float kfr = a00r - qr, kfi = a00i - qi;
        const float fi  = 0.5f * yBv;
        grow[lB] = make_float2(kfr - kfi * fi, kfi + kfr * fi);
    }

    // ---- Nyquist bin l=4096 (P/Q path at y4), wave 0 of chunk 7 ----
    if (chunk == 7 && tid < 64) {
        const int n = tid;
        const int k = n >> 1, o = n & 1;
        const float* base = (const float*)&s_pp[k];
        const float nwisq_s = base[0 + o];
        const float c1_s    = base[2 + o];
        const float c2_s    = base[4 + o];
        // rev = 0.25 -> cos = 0 exactly; clamp reproduces reference's f32 z ~ 4.58e7
        const float y4 = 2.0f * __builtin_amdgcn_rcpf(4.3711388e-8f);
        const float y4sq = y4 * y4;
        const float g  = y4sq + nwisq_s;
        const float dd = fmaf(g, g, fmaf(c2_s, y4sq, c1_s));
        const float ir = __builtin_amdgcn_rcpf(dd);
        const float gir = g * ir;
        float e[8];
        #pragma unroll
        for (int j = 0; j < 4; ++j) {
            const float P = base[(8  + 8 * j) + o];
            const float Q = base[(10 + 8 * j) + o];
            const float Cc = base[(12 + 8 * j) + o];
            const float D = base[(14 + 8 * j) + o];
            e[2 * j]     = fmaf(P, gir, Q * ir);
            e[2 * j + 1] = fmaf(Cc, gir, D * ir);   // imag / y4
        }
        #pragma unroll
        for (int m = 1; m < 64; m <<= 1) {
            #pragma unroll
            for (int t = 0; t < 8; ++t) e[t] += __shfl_xor(e[t], m);
        }
        if (tid == 0) {
            const float dty4 = dt * y4;
            const float a00r = e[0] * dt, a00i = e[1] * dty4;
            const float a01r = e[2] * dt, a01i = e[3] * dty4;
            const float a10r = e[4] * dt, a10i = e[5] * dty4;
            const float a11r = e[6] * dt, a11i = e[7] * dty4;
            const float numr = a01r * a10r - a01i * a10i;
            const float numi = a01r * a10i + a01i * a10r;
            const float dwr = 1.f + a11r, dwi = a11i;
            const float idw = __builtin_amdgcn_rcpf(dwr * dwr + dwi * dwi);
            const float qr = (numr * dwr + numi * dwi) * idw;
            const float qi = (numi * dwr - numr * dwi) * idw;
            const float kfr = a00r - qr, kfi = a00i - qi;
            const float fi  = 0.5f * y4;
            nyq[h] = make_float2(kfr - kfi * fi, kfi + kfr * fi);
        }
    }
}

// ---------------- Kernel B: pack + radix-4 Stockham iFFT + store -------------
__global__ __launch_bounds__(NTB)
void ifft_phase(float* __restrict__ io, const float2* __restrict__ nyq)
{
    __shared__ float2 sA[NHALF];
    __shared__ float2 sB[NHALF];

    const int h   = blockIdx.x;
    const int tid = threadIdx.x;
    float2* grow = (float2*)(io + (size_t)h * LL);

    // pack irfft(L) into complex iFFT(L/2), natural order:
    // Z[k] = (1/L)[(G[k]+conj(G[N-k])) + i*e^{+2pi i k/L}(G[k]-conj(G[N-k]))]
    #pragma unroll
    for (int ki = 0; ki < 4; ++ki) {
        const int k = tid + NTB * ki;
        const float2 Gk = grow[k];
        const float2 Gn = (k == 0) ? nyq[h] : grow[NHALF - k];
        const float Ar = Gk.x + Gn.x, Ai = Gk.y - Gn.y;
        const float Br = Gk.x - Gn.x, Bi = Gk.y + Gn.y;
        const float rev = (float)k * 1.220703125e-4f;   // k/8192
        const float cw = __builtin_amdgcn_cosf(rev);
        const float sw = __builtin_amdgcn_sinf(rev);
        const float sc = 1.0f / (float)LL;
        sA[k] = make_float2((Ar - cw * Bi - sw * Br) * sc,
                            (Ai + cw * Br - sw * Bi) * sc);
    }
    __syncthreads();

    // 6 radix-4 Stockham stages (inverse FFT, e^{+i} twiddles), ping-pong sA<->sB
    float2* pin  = sA;
    float2* pout = sB;
    #pragma unroll
    for (int s = 0; s < 6; ++s) {
        const int ls2 = 2 * s;
        const int Ls  = 1 << ls2;
        const int j   = tid;
        const int k   = j & (Ls - 1);
        const int tb  = k << (10 - ls2);
        const float fr = (float)tb * 2.44140625e-4f;    // tb/4096 revolutions
        const float c1 = __builtin_amdgcn_cosf(fr);
        const float s1 = __builtin_amdgcn_sinf(fr);
        const float c2 = __builtin_amdgcn_cosf(2.0f * fr);
        const float s2 = __builtin_amdgcn_sinf(2.0f * fr);
        const float c3 = __builtin_amdgcn_cosf(3.0f * fr);
        const float s3 = __builtin_amdgcn_sinf(3.0f * fr);
        float2 u0 = pin[j];
        float2 u1 = pin[j + 1024];
        float2 u2 = pin[j + 2048];
        float2 u3 = pin[j + 3072];
        float a, b;
        a = u1.x * c1 - u1.y * s1;  b = u1.x * s1 + u1.y * c1;  u1 = make_float2(a, b);
        a = u2.x * c2 - u2.y * s2;  b = u2.x * s2 + u2.y * c2;  u2 = make_float2(a, b);
        a = u3.x * c3 - u3.y * s3;  b = u3.x * s3 + u3.y * c3;  u3 = make_float2(a, b);
        const float t0r = u0.x + u2.x, t0i = u0.y + u2.y;
        const float t1r = u0.x - u2.x, t1i = u0.y - u2.y;
        const float t2r = u1.x + u3.x, t2i = u1.y + u3.y;
        const float t3r = u3.y - u1.y, t3i = u1.x - u3.x;   // i*(u1-u3)
        const int ob = ((j - k) << 2) + k;
        pout[ob]          = make_float2(t0r + t2r, t0i + t2i);
        pout[ob + Ls]     = make_float2(t1r + t3r, t1i + t3i);
        pout[ob + 2 * Ls] = make_float2(t0r - t2r, t0i - t2i);
        pout[ob + 3 * Ls] = make_float2(t1r - t3r, t1i - t3i);
        float2* tmp = pin; pin = pout; pout = tmp;
        __syncthreads();
    }

    // final data lands in sA; x[2j]=Re, x[2j+1]=Im -> coalesced float2 store
    #pragma unroll
    for (int ji = 0; ji < 4; ++ji) {
        const int j = tid + NTB * ji;
        grow[j] = sA[j];
    }
}

extern "C" void kernel_launch(void* const* d_in, const int* in_sizes, int n_in,
                              void* d_out, int out_size, void* d_ws, size_t ws_size,
                              hipStream_t stream) {
    const float* w   = (const float*)d_in[0];
    const float* p   = (const float*)d_in[1];
    const float* q   = (const float*)d_in[2];
    const float* B   = (const float*)d_in[3];
    const float* C   = (const float*)d_in[4];
    const float* ldt = (const float*)d_in[5];
    float*  spec = (float*)d_out;          // spectrum staged in-place in d_out
    float2* nyq  = (float2*)d_ws;          // 256 * 8 B Nyquist bins

    dim3 gridA(8, NUM_H);
    cauchy_phase<<<gridA, NTA, 0, stream>>>(w, p, q, B, C, ldt, spec, nyq);
    ifft_phase<<<NUM_H, NTB, 0, stream>>>(spec, nyq);
}

// Round 19
// 43.555 us; speedup vs baseline: 2.0795x; 1.0051x over previous
//
#include <hip/hip_runtime.h>
#include <math.h>

#define NUM_H 256
#define NP    64        // poles per h
#define LL    8192      // sequence length
#define NHALF 4096      // LL/2 (complex FFT size)
#define NTA   256       // threads, Cauchy kernel
#define NTB   1024      // threads, FFT kernel

typedef float v2f __attribute__((ext_vector_type(2)));

// v_sin_f32 / v_cos_f32 take input in REVOLUTIONS (D = sin(S0 * 2pi)).

// P/Q strength-reduced per-pole coefficients (r14/r16/r18-proven):
//   g = y^2 - wi^2; dd = d1*d2 = g^2 + (c2*y^2 + c1); ir = 1/dd
//   real contrib = P*g*ir + Q*ir
//   imag contrib = y * (C*g*ir + D*ir)    [y hoisted out of the pole sum]
//   c1 = wz^2 + 2wz*wi^2; c2 = 2wz; c6 = 4wi^2 + 2wz; wz = wr^2; wx = -wr
//   P = 2(wx*vr + wi*vi);  Q = wx*c6*vr - 2wi*wz*vi
//   C = -2vr;              D = -2wz*vr + 4wx*wi*vi
// Table: 20 v2f per pole-pair, field i at float offset 2i+o (o = pole parity).
//
// HARD RULES (from failures): NO pointer-indexing across asm-tied locals
// (r8/r15 compile timeouts); NO #pragma unroll >1 around the tied-asm loop
// (r11/r17 silent miscompiles). r19 delta vs r18: bin A and bin B
// denominator chains INTERLEAVED in one asm block (dep pairs >= 2 apart).

struct PolePairPQ { v2f fld[20]; };

// ---------------- Kernel A: Cauchy sum + Woodbury -> spectrum ----------------
__global__ __launch_bounds__(NTA)
void cauchy_phase(const float* __restrict__ w_ri,
                  const float* __restrict__ p_ri,
                  const float* __restrict__ q_ri,
                  const float* __restrict__ B_ri,
                  const float* __restrict__ C_ri,
                  const float* __restrict__ log_dt,
                  float*       __restrict__ spec,   // (H, 4096) float2 rows (= d_out)
                  float2*      __restrict__ nyq)    // (H,) Nyquist bins (= d_ws)
{
    __shared__ PolePairPQ s_pp[NP / 2];

    const int h     = blockIdx.y;
    const int chunk = blockIdx.x;      // 8 chunks of 256 low bins
    const int tid   = threadIdx.x;
    const float dt  = expf(log_dt[h]);

    if (tid < NP) {
        const int n = tid;
        const int k = n >> 1, o = n & 1;
        const float2 w = ((const float2*)w_ri)[h * NP + n];
        const float2 p = ((const float2*)p_ri)[h * NP + n];
        const float2 q = ((const float2*)q_ri)[h * NP + n];
        const float2 B = ((const float2*)B_ri)[h * NP + n];
        const float2 C = ((const float2*)C_ri)[h * NP + n];
        const float wr = w.x * dt, wi = w.y * dt;
        const float wz = wr * wr, wisq = wi * wi, wx = -wr;
        const float c6 = 4.f * wisq + 2.f * wz;
        const float vrs[4] = {B.x * C.x + B.y * C.y, p.x * C.x + p.y * C.y,
                              B.x * q.x + B.y * q.y, p.x * q.x + p.y * q.y};
        const float vis[4] = {B.y * C.x - B.x * C.y, p.y * C.x - p.x * C.y,
                              B.y * q.x - B.x * q.y, p.y * q.x - p.x * q.y};
        float* base = (float*)&s_pp[k];
        base[0 + o] = -wisq;                        // nwisq
        base[2 + o] = wz * wz + 2.f * wz * wisq;    // c1
        base[4 + o] = 2.f * wz;                     // c2
        base[6 + o] = wi;                           // pad/wi
        #pragma unroll
        for (int j = 0; j < 4; ++j) {
            base[(8  + 8 * j) + o] = 2.f * (wx * vrs[j] + wi * vis[j]);           // P
            base[(10 + 8 * j) + o] = wx * c6 * vrs[j] - 2.f * wi * wz * vis[j];   // Q
            base[(12 + 8 * j) + o] = -2.f * vrs[j];                               // C
            base[(14 + 8 * j) + o] = -2.f * wz * vrs[j] + 4.f * wx * wi * vis[j]; // D
        }
    }
    __syncthreads();

    const int lA = (chunk << 8) + tid;       // 0..2047
    const int lB = lA + 2048;                // 2048..4095
    // y = Im(z) = 2*tan(pi*l/L); rev = l/16384 (exact dyadic)
    float yS[2];
    #pragma unroll
    for (int b = 0; b < 2; ++b) {
        const int l = lA + (b << 11);
        const float rev = (float)l * 6.103515625e-5f;
        const float sn  = __builtin_amdgcn_sinf(rev);
        const float cn  = fmaxf(__builtin_amdgcn_cosf(rev), 4.3711388e-8f);
        yS[b] = 2.0f * sn * __builtin_amdgcn_rcpf(cn);
    }
    const float yAv = yS[0], yBv = yS[1];
    const v2f yAsq = {yAv * yAv, yAv * yAv};
    const v2f yBsq = {yBv * yBv, yBv * yBv};

    v2f rA0 = 0.f, iA0 = 0.f, rA1 = 0.f, iA1 = 0.f;
    v2f rA2 = 0.f, iA2 = 0.f, rA3 = 0.f, iA3 = 0.f;
    v2f rB0 = 0.f, iB0 = 0.f, rB1 = 0.f, iB1 = 0.f;
    v2f rB2 = 0.f, iB2 = 0.f, rB3 = 0.f, iB3 = 0.f;
    #pragma unroll 1
    for (int k = 0; k < NP / 2; ++k) {
        const v2f* f = s_pp[k].fld;
        const v2f nwisq = f[0], c1 = f[1], c2 = f[2];
        const v2f P0 = f[4],  Q0 = f[5],  C0 = f[6],  D0 = f[7];
        const v2f P1 = f[8],  Q1 = f[9],  C1 = f[10], D1 = f[11];
        const v2f P2 = f[12], Q2 = f[13], C2 = f[14], D2 = f[15];
        const v2f P3 = f[16], Q3 = f[17], C3 = f[18], D3 = f[19];

        // ---- both bins' denominators, interleaved (dep pairs >= 2 apart) ----
        v2f gA, gB, inA, inB, ddA, ddB;
        asm("v_pk_add_f32 %0, %6, %8\n\t"        // gA  = yA^2 + (-wi^2)
            "v_pk_add_f32 %1, %7, %8\n\t"        // gB  = yB^2 + (-wi^2)
            "v_pk_fma_f32 %2, %9, %6, %10\n\t"   // inA = c2*yA^2 + c1
            "v_pk_fma_f32 %3, %9, %7, %10\n\t"   // inB = c2*yB^2 + c1
            "v_pk_fma_f32 %4, %0, %0, %2\n\t"    // ddA = gA*gA + inA
            "v_pk_fma_f32 %5, %1, %1, %3"        // ddB = gB*gB + inB
            : "=&v"(gA), "=&v"(gB), "=&v"(inA), "=&v"(inB), "=&v"(ddA), "=&v"(ddB)
            : "v"(yAsq), "v"(yBsq), "v"(nwisq), "v"(c2), "v"(c1));

        const v2f irA = {__builtin_amdgcn_rcpf(ddA.x), __builtin_amdgcn_rcpf(ddA.y)};
        const v2f irB = {__builtin_amdgcn_rcpf(ddB.x), __builtin_amdgcn_rcpf(ddB.y)};

        v2f girA, girB;
        asm("v_pk_mul_f32 %0, %2, %3\n\t"        // girA = gA * irA
            "v_pk_mul_f32 %1, %4, %5"            // girB = gB * irB
            : "=&v"(girA), "=&v"(girB)
            : "v"(gA), "v"(irA), "v"(gB), "v"(irB));

        // ---- accumulate bin A: pass 1 = all accums x gir, pass 2 = x ir ----
        asm("v_pk_fma_f32 %0, %10, %8, %0\n\t"   // r0 += P0*gir
            "v_pk_fma_f32 %1, %12, %8, %1\n\t"   // i0 += C0*gir
            "v_pk_fma_f32 %2, %14, %8, %2\n\t"   // r1 += P1*gir
            "v_pk_fma_f32 %3, %16, %8, %3\n\t"   // i1 += C1*gir
            "v_pk_fma_f32 %4, %18, %8, %4\n\t"   // r2 += P2*gir
            "v_pk_fma_f32 %5, %20, %8, %5\n\t"   // i2 += C2*gir
            "v_pk_fma_f32 %6, %22, %8, %6\n\t"   // r3 += P3*gir
            "v_pk_fma_f32 %7, %24, %8, %7\n\t"   // i3 += C3*gir
            "v_pk_fma_f32 %0, %11, %9, %0\n\t"   // r0 += Q0*ir
            "v_pk_fma_f32 %1, %13, %9, %1\n\t"   // i0 += D0*ir
            "v_pk_fma_f32 %2, %15, %9, %2\n\t"
            "v_pk_fma_f32 %3, %17, %9, %3\n\t"
            "v_pk_fma_f32 %4, %19, %9, %4\n\t"
            "v_pk_fma_f32 %5, %21, %9, %5\n\t"
            "v_pk_fma_f32 %6, %23, %9, %6\n\t"
            "v_pk_fma_f32 %7, %25, %9, %7"
            : "+v"(rA0), "+v"(iA0), "+v"(rA1), "+v"(iA1),
              "+v"(rA2), "+v"(iA2), "+v"(rA3), "+v"(iA3)
            : "v"(girA), "v"(irA),
              "v"(P0), "v"(Q0), "v"(C0), "v"(D0),
              "v"(P1), "v"(Q1), "v"(C1), "v"(D1),
              "v"(P2), "v"(Q2), "v"(C2), "v"(D2),
              "v"(P3), "v"(Q3), "v"(C3), "v"(D3));

        // ---- accumulate bin B ----
        asm("v_pk_fma_f32 %0, %10, %8, %0\n\t"
            "v_pk_fma_f32 %1, %12, %8, %1\n\t"
            "v_pk_fma_f32 %2, %14, %8, %2\n\t"
            "v_pk_fma_f32 %3, %16, %8, %3\n\t"
            "v_pk_fma_f32 %4, %18, %8, %4\n\t"
            "v_pk_fma_f32 %5, %20, %8, %5\n\t"
            "v_pk_fma_f32 %6, %22, %8, %6\n\t"
            "v_pk_fma_f32 %7, %24, %8, %7\n\t"
            "v_pk_fma_f32 %0, %11, %9, %0\n\t"
            "v_pk_fma_f32 %1, %13, %9, %1\n\t"
            "v_pk_fma_f32 %2, %15, %9, %2\n\t"
            "v_pk_fma_f32 %3, %17, %9, %3\n\t"
            "v_pk_fma_f32 %4, %19, %9, %4\n\t"
            "v_pk_fma_f32 %5, %21, %9, %5\n\t"
            "v_pk_fma_f32 %6, %23, %9, %6\n\t"
            "v_pk_fma_f32 %7, %25, %9, %7"
            : "+v"(rB0), "+v"(iB0), "+v"(rB1), "+v"(iB1),
              "+v"(rB2), "+v"(iB2), "+v"(rB3), "+v"(iB3)
            : "v"(girB), "v"(irB),
              "v"(P0), "v"(Q0), "v"(C0), "v"(D0),
              "v"(P1), "v"(Q1), "v"(C1), "v"(D1),
              "v"(P2), "v"(Q2), "v"(C2), "v"(D2),
              "v"(P3), "v"(Q3), "v"(C3), "v"(D3));
    }

    // horizontal add, apply dt (and y to imag), Woodbury, bilinear — per bin
    float2* grow = (float2*)(spec + (size_t)h * LL);
    {
        const float dty = dt * yAv;
        const float a00r = (rA0.x + rA0.y) * dt, a00i = (iA0.x + iA0.y) * dty;
        const float a01r = (rA1.x + rA1.y) * dt, a01i = (iA1.x + iA1.y) * dty;
        const float a10r = (rA2.x + rA2.y) * dt, a10i = (iA2.x + iA2.y) * dty;
        const float a11r = (rA3.x + rA3.y) * dt, a11i = (iA3.x + iA3.y) * dty;
        const float numr = a01r * a10r - a01i * a10i;
        const float numi = a01r * a10i + a01i * a10r;
        const float dwr = 1.f + a11r, dwi = a11i;
        const float idw = __builtin_amdgcn_rcpf(dwr * dwr + dwi * dwi);
        const float qr = (numr * dwr + numi * dwi) * idw;
        const float qi = (numi * dwr - numr * dwi) * idw;
        const float kfr = a00r - qr, kfi = a00i - qi;
        const float fi  = 0.5f * yAv;      // 2/(1+nodes) = 1 + i*tan(pi*l/L)
        grow[lA] = make_float2(kfr - kfi * fi, kfi + kfr * fi);
    }
    {
        const float dty = dt * yBv;
        const float a00r = (rB0.x + rB0.y) * dt, a00i = (iB0.x + iB0.y) * dty;
        const float a01r = (rB1.x + rB1.y) * dt, a01i = (iB1.x + iB1.y) * dty;
        const float a10r = (rB2.x + rB2.y) * dt, a10i = (iB2.x + iB2.y) * dty;
        const float a11r = (rB3.x + rB3.y) * dt, a11i = (iB3.x + iB3.y) * dty;
        const float numr = a01r * a10r - a01i * a10i;
        const float numi = a01r * a10i + a01i * a10r;
        const float dwr = 1.f + a11r, dwi = a11i;
        const float idw = __builtin_amdgcn_rcpf(dwr * dwr + dwi * dwi);
        const float qr = (numr * dwr + numi * dwi) * idw;
        const float qi = (numi * dwr - numr * dwi) * idw;
        const float kfr = a00r - qr, kfi = a00i - qi;
        const float fi  = 0.5f * yBv;
        grow[lB] = make_float2(kfr - kfi * fi, kfi + kfr * fi);
    }

    // ---- Nyquist bin l=4096 (P/Q path at y4), wave 0 of chunk 7 ----
    if (chunk == 7 && tid < 64) {
        const int n = tid;
        const int k = n >> 1, o = n & 1;
        const float* base = (const float*)&s_pp[k];
        const float nwisq_s = base[0 + o];
        const float c1_s    = base[2 + o];
        const float c2_s    = base[4 + o];
        // rev = 0.25 -> cos = 0 exactly; clamp reproduces reference's f32 z ~ 4.58e7
        const float y4 = 2.0f * __builtin_amdgcn_rcpf(4.3711388e-8f);
        const float y4sq = y4 * y4;
        const float g  = y4sq + nwisq_s;
        const float dd = fmaf(g, g, fmaf(c2_s, y4sq, c1_s));
        const float ir = __builtin_amdgcn_rcpf(dd);
        const float gir = g * ir;
        float e[8];
        #pragma unroll
        for (int j = 0; j < 4; ++j) {
            const float P = base[(8  + 8 * j) + o];
            const float Q = base[(10 + 8 * j) + o];
            const float Cc = base[(12 + 8 * j) + o];
            const float D = base[(14 + 8 * j) + o];
            e[2 * j]     = fmaf(P, gir, Q * ir);
            e[2 * j + 1] = fmaf(Cc, gir, D * ir);   // imag / y4
        }
        #pragma unroll
        for (int m = 1; m < 64; m <<= 1) {
            #pragma unroll
            for (int t = 0; t < 8; ++t) e[t] += __shfl_xor(e[t], m);
        }
        if (tid == 0) {
            const float dty4 = dt * y4;
            const float a00r = e[0] * dt, a00i = e[1] * dty4;
            const float a01r = e[2] * dt, a01i = e[3] * dty4;
            const float a10r = e[4] * dt, a10i = e[5] * dty4;
            const float a11r = e[6] * dt, a11i = e[7] * dty4;
            const float numr = a01r * a10r - a01i * a10i;
            const float numi = a01r * a10i + a01i * a10r;
            const float dwr = 1.f + a11r, dwi = a11i;
            const float idw = __builtin_amdgcn_rcpf(dwr * dwr + dwi * dwi);
            const float qr = (numr * dwr + numi * dwi) * idw;
            const float qi = (numi * dwr - numr * dwi) * idw;
            const float kfr = a00r - qr, kfi = a00i - qi;
            const float fi  = 0.5f * y4;
            nyq[h] = make_float2(kfr - kfi * fi, kfi + kfr * fi);
        }
    }
}

// ---------------- Kernel B: pack + radix-4 Stockham iFFT + store -------------
__global__ __launch_bounds__(NTB)
void ifft_phase(float* __restrict__ io, const float2* __restrict__ nyq)
{
    __shared__ float2 sA[NHALF];
    __shared__ float2 sB[NHALF];

    const int h   = blockIdx.x;
    const int tid = threadIdx.x;
    float2* grow = (float2*)(io + (size_t)h * LL);

    // pack irfft(L) into complex iFFT(L/2), natural order:
    // Z[k] = (1/L)[(G[k]+conj(G[N-k])) + i*e^{+2pi i k/L}(G[k]-conj(G[N-k]))]
    #pragma unroll
    for (int ki = 0; ki < 4; ++ki) {
        const int k = tid + NTB * ki;
        const float2 Gk = grow[k];
        const float2 Gn = (k == 0) ? nyq[h] : grow[NHALF - k];
        const float Ar = Gk.x + Gn.x, Ai = Gk.y - Gn.y;
        const float Br = Gk.x - Gn.x, Bi = Gk.y + Gn.y;
        const float rev = (float)k * 1.220703125e-4f;   // k/8192
        const float cw = __builtin_amdgcn_cosf(rev);
        const float sw = __builtin_amdgcn_sinf(rev);
        const float sc = 1.0f / (float)LL;
        sA[k] = make_float2((Ar - cw * Bi - sw * Br) * sc,
                            (Ai + cw * Br - sw * Bi) * sc);
    }
    __syncthreads();

    // 6 radix-4 Stockham stages (inverse FFT, e^{+i} twiddles), ping-pong sA<->sB
    float2* pin  = sA;
    float2* pout = sB;
    #pragma unroll
    for (int s = 0; s < 6; ++s) {
        const int ls2 = 2 * s;
        const int Ls  = 1 << ls2;
        const int j   = tid;
        const int k   = j & (Ls - 1);
        const int tb  = k << (10 - ls2);
        const float fr = (float)tb * 2.44140625e-4f;    // tb/4096 revolutions
        const float c1 = __builtin_amdgcn_cosf(fr);
        const float s1 = __builtin_amdgcn_sinf(fr);
        const float c2 = __builtin_amdgcn_cosf(2.0f * fr);
        const float s2 = __builtin_amdgcn_sinf(2.0f * fr);
        const float c3 = __builtin_amdgcn_cosf(3.0f * fr);
        const float s3 = __builtin_amdgcn_sinf(3.0f * fr);
        float2 u0 = pin[j];
        float2 u1 = pin[j + 1024];
        float2 u2 = pin[j + 2048];
        float2 u3 = pin[j + 3072];
        float a, b;
        a = u1.x * c1 - u1.y * s1;  b = u1.x * s1 + u1.y * c1;  u1 = make_float2(a, b);
        a = u2.x * c2 - u2.y * s2;  b = u2.x * s2 + u2.y * c2;  u2 = make_float2(a, b);
        a = u3.x * c3 - u3.y * s3;  b = u3.x * s3 + u3.y * c3;  u3 = make_float2(a, b);
        const float t0r = u0.x + u2.x, t0i = u0.y + u2.y;
        const float t1r = u0.x - u2.x, t1i = u0.y - u2.y;
        const float t2r = u1.x + u3.x, t2i = u1.y + u3.y;
        const float t3r = u3.y - u1.y, t3i = u1.x - u3.x;   // i*(u1-u3)
        const int ob = ((j - k) << 2) + k;
        pout[ob]          = make_float2(t0r + t2r, t0i + t2i);
        pout[ob + Ls]     = make_float2(t1r + t3r, t1i + t3i);
        pout[ob + 2 * Ls] = make_float2(t0r - t2r, t0i - t2i);
        pout[ob + 3 * Ls] = make_float2(t1r - t3r, t1i - t3i);
        float2* tmp = pin; pin = pout; pout = tmp;
        __syncthreads();
    }

    // final data lands in sA; x[2j]=Re, x[2j+1]=Im -> coalesced float2 store
    #pragma unroll
    for (int ji = 0; ji < 4; ++ji) {
        const int j = tid + NTB * ji;
        grow[j] = sA[j];
    }
}

extern "C" void kernel_launch(void* const* d_in, const int* in_sizes, int n_in,
                              void* d_out, int out_size, void* d_ws, size_t ws_size,
                              hipStream_t stream) {
    const float* w   = (const float*)d_in[0];
    const float* p   = (const float*)d_in[1];
    const float* q   = (const float*)d_in[2];
    const float* B   = (const float*)d_in[3];
    const float* C   = (const float*)d_in[4];
    const float* ldt = (const float*)d_in[5];
    float*  spec = (float*)d_out;          // spectrum staged in-place in d_out
    float2* nyq  = (float2*)d_ws;          // 256 * 8 B Nyquist bins

    dim3 gridA(8, NUM_H);
    cauchy_phase<<<gridA, NTA, 0, stream>>>(w, p, q, B, C, ldt, spec, nyq);
    ifft_phase<<<NUM_H, NTB, 0, stream>>>(spec, nyq);
}